// Round 3
// baseline (556.434 us; speedup 1.0000x reference)
//
#include <hip/hip_runtime.h>

#define USER_NUM 100000
#define ITEM_NUM 50000
#define N_NODES  150000   // USER_NUM + ITEM_NUM
#define EMB_DIM  64
#define NNZ      4800000

#define CB_SHIFT 10
#define ROWS_PER_CB 1024
#define NCB ((N_NODES + ROWS_PER_CB - 1) / ROWS_PER_CB)   // 147
#define CB_CAP 34000            // expected 32.7k edges/bucket, ~7 sigma slack
#define TILE 8192
#define NTILES ((NNZ + TILE - 1) / TILE)  // 586
#define EPT 32                  // edges per thread in partition

// bf16 helpers: unpack a uint32 holding two bf16 (low ushort = even elem)
__device__ __forceinline__ float bflo(unsigned u) {
    return __uint_as_float(u << 16);
}
__device__ __forceinline__ float bfhi(unsigned u) {
    return __uint_as_float(u & 0xFFFF0000u);
}
// fp32 -> bf16 (RNE), returned in low 16 bits
__device__ __forceinline__ unsigned f2bf(float f) {
    unsigned u = __float_as_uint(f);
    return (u + 0x7FFFu + ((u >> 16) & 1u)) >> 16;
}

// ---------------------------------------------------------------------------
// init: xb = bf16(concat(user_emb, item_emb)), packed 8 elems = uint4/thread.
// ---------------------------------------------------------------------------
__global__ void lgcn_init(const float4* __restrict__ user,
                          const float4* __restrict__ item,
                          uint4* __restrict__ xb) {
    int i = blockIdx.x * blockDim.x + threadIdx.x;   // chunk of 8 floats
    if (i >= N_NODES * 8) return;
    const int user_chunks = USER_NUM * 8;
    float4 f0, f1;
    if (i < user_chunks) {
        f0 = user[i * 2];
        f1 = user[i * 2 + 1];
    } else {
        f0 = item[(i - user_chunks) * 2];
        f1 = item[(i - user_chunks) * 2 + 1];
    }
    uint4 p;
    p.x = f2bf(f0.x) | (f2bf(f0.y) << 16);
    p.y = f2bf(f0.z) | (f2bf(f0.w) << 16);
    p.z = f2bf(f1.x) | (f2bf(f1.y) << 16);
    p.w = f2bf(f1.z) | (f2bf(f1.w) << 16);
    xb[i] = p;
}

// ---------------------------------------------------------------------------
// setup: bucket cursors + degree histogram zero
// ---------------------------------------------------------------------------
__global__ void lgcn_setup(int* __restrict__ bucket_cursor,
                           int* __restrict__ deg_hist) {
    int b = blockIdx.x * blockDim.x + threadIdx.x;
    if (b < NCB) bucket_cursor[b] = b * CB_CAP;
    if (b < 128) deg_hist[b] = 0;
}

// ---------------------------------------------------------------------------
// partition: per 8192-edge tile, in-LDS counting sort by coarse bucket,
// then write staging in sorted slot order.               (unchanged)
// ---------------------------------------------------------------------------
__global__ __launch_bounds__(256) void lgcn_partition(
    const int* __restrict__ row,
    const int* __restrict__ col,
    const float* __restrict__ vals,
    int* __restrict__ bucket_cursor,  // pre-init to b*CB_CAP
    int2* __restrict__ t_cv) {
    __shared__ int hist[NCB];
    __shared__ int excl[NCB];
    __shared__ int delta[NCB];
    __shared__ unsigned lslot[TILE];
    __shared__ int sscan[256];

    int tid = threadIdx.x;
    int tileStart = blockIdx.x * TILE;
    int tileCount = NNZ - tileStart;
    if (tileCount > TILE) tileCount = TILE;

    for (int b = tid; b < NCB; b += 256) hist[b] = 0;
    __syncthreads();

    int rws[EPT];
#pragma unroll
    for (int k = 0; k < EPT; ++k) {
        int le = tid + k * 256;
        int r = -1;
        if (le < tileCount) {
            r = row[tileStart + le];
            atomicAdd(&hist[r >> CB_SHIFT], 1);
        }
        rws[k] = r;
    }
    __syncthreads();

    int h = (tid < NCB) ? hist[tid] : 0;
    sscan[tid] = h;
    __syncthreads();
    for (int off = 1; off < 256; off <<= 1) {
        int x = (tid >= off) ? sscan[tid - off] : 0;
        __syncthreads();
        sscan[tid] += x;
        __syncthreads();
    }
    if (tid < NCB) {
        int ex = sscan[tid] - h;
        excl[tid] = ex;
        int rb = h ? atomicAdd(&bucket_cursor[tid], h) : 0;
        delta[tid] = rb - ex;
    }
    __syncthreads();

#pragma unroll
    for (int k = 0; k < EPT; ++k) {
        int le = tid + k * 256;
        if (le < tileCount) {
            int r = rws[k];
            int b = r >> CB_SHIFT;
            int lp = atomicAdd(&excl[b], 1);
            lslot[lp] = ((unsigned)b << 23) |
                        ((unsigned)(r & (ROWS_PER_CB - 1)) << 13) |
                        (unsigned)le;
        }
    }
    __syncthreads();

    for (int i = tid; i < tileCount; i += 256) {
        unsigned s = lslot[i];
        int b = s >> 23;
        int rlo = (s >> 13) & (ROWS_PER_CB - 1);
        int le = s & 8191;
        int e = tileStart + le;
        int gpos = delta[b] + i;
        if (gpos < (b + 1) * CB_CAP) {
            t_cv[gpos] = make_int2((rlo << 18) | col[e],
                                   __float_as_int(vals[e]));
        }
    }
}

// ---------------------------------------------------------------------------
// finalize: one 1024-thread block per coarse bucket.      (unchanged)
// ---------------------------------------------------------------------------
__global__ __launch_bounds__(1024) void lgcn_finalize(
    const int* __restrict__ bucket_cursor,
    const int2* __restrict__ t_cv,
    int2* __restrict__ csr_cv,
    int2* __restrict__ row_se) {
    __shared__ int hist[ROWS_PER_CB];
    __shared__ int cur[ROWS_PER_CB];
    __shared__ int sscan[1024];
    int t = threadIdx.x;
    int b = blockIdx.x;

    int v = 0;
    if (t < NCB) {
        int cb = bucket_cursor[t] - t * CB_CAP;
        v = (cb > CB_CAP) ? CB_CAP : cb;
    }
    if (t < 256) sscan[t] = v;
    __syncthreads();
    for (int off = 1; off < 256; off <<= 1) {
        int x = 0;
        if (t < 256 && t >= off) x = sscan[t - off];
        __syncthreads();
        if (t < 256) sscan[t] += x;
        __syncthreads();
    }
    int prev = (b == 0) ? 0 : sscan[b - 1];
    int bbase = prev;
    int count = sscan[b] - prev;
    __syncthreads();

    int lo = b * ROWS_PER_CB;
    int nrows = N_NODES - lo;
    if (nrows > ROWS_PER_CB) nrows = ROWS_PER_CB;

    hist[t] = 0;
    __syncthreads();

    int base = b * CB_CAP;
    int eEnd = base + count;
    int e = base + t;
    for (; e + 3 * 1024 < eEnd; e += 4 * 1024) {
        int2 c0 = t_cv[e];
        int2 c1 = t_cv[e + 1024];
        int2 c2 = t_cv[e + 2048];
        int2 c3 = t_cv[e + 3072];
        atomicAdd(&hist[(unsigned)c0.x >> 18], 1);
        atomicAdd(&hist[(unsigned)c1.x >> 18], 1);
        atomicAdd(&hist[(unsigned)c2.x >> 18], 1);
        atomicAdd(&hist[(unsigned)c3.x >> 18], 1);
    }
    for (; e < eEnd; e += 1024)
        atomicAdd(&hist[(unsigned)t_cv[e].x >> 18], 1);
    __syncthreads();

    int h = hist[t];
    sscan[t] = h;
    __syncthreads();
    for (int off = 1; off < 1024; off <<= 1) {
        int x = (t >= off) ? sscan[t - off] : 0;
        __syncthreads();
        sscan[t] += x;
        __syncthreads();
    }
    int p = bbase + sscan[t] - h;
    if (t < nrows) {
        row_se[lo + t] = make_int2(p, p + h);
        cur[t] = p;
    }
    __syncthreads();

    e = base + t;
    for (; e + 3 * 1024 < eEnd; e += 4 * 1024) {
        int2 c0 = t_cv[e];
        int2 c1 = t_cv[e + 1024];
        int2 c2 = t_cv[e + 2048];
        int2 c3 = t_cv[e + 3072];
        int p0 = atomicAdd(&cur[(unsigned)c0.x >> 18], 1);
        int p1 = atomicAdd(&cur[(unsigned)c1.x >> 18], 1);
        int p2 = atomicAdd(&cur[(unsigned)c2.x >> 18], 1);
        int p3 = atomicAdd(&cur[(unsigned)c3.x >> 18], 1);
        csr_cv[p0] = make_int2(c0.x & 0x3FFFF, c0.y);
        csr_cv[p1] = make_int2(c1.x & 0x3FFFF, c1.y);
        csr_cv[p2] = make_int2(c2.x & 0x3FFFF, c2.y);
        csr_cv[p3] = make_int2(c3.x & 0x3FFFF, c3.y);
    }
    for (; e < eEnd; e += 1024) {
        int2 cv = t_cv[e];
        int pos = atomicAdd(&cur[(unsigned)cv.x >> 18], 1);
        csr_cv[pos] = make_int2(cv.x & 0x3FFFF, cv.y);
    }
}

// ---------------------------------------------------------------------------
// degree counting-sort (3 small kernels): rows processed in DESCENDING degree
// order so the 8 rows sharing a wave have ~equal edge counts (no divergence)
// and end-of-kernel stragglers are the lightest rows.
// ---------------------------------------------------------------------------
__global__ __launch_bounds__(256) void lgcn_deghist(
    const int2* __restrict__ row_se, int* __restrict__ deg_hist) {
    __shared__ int lh[128];
    int t = threadIdx.x;
    if (t < 128) lh[t] = 0;
    __syncthreads();
    int r = blockIdx.x * 256 + t;
    if (r < N_NODES) {
        int2 se = row_se[r];
        int d = se.y - se.x;
        if (d > 127) d = 127;
        atomicAdd(&lh[d], 1);
    }
    __syncthreads();
    if (t < 128 && lh[t]) atomicAdd(&deg_hist[t], lh[t]);
}

__global__ void lgcn_degscan(const int* __restrict__ deg_hist,
                             int* __restrict__ deg_base) {
    __shared__ int s[128];
    int t = threadIdx.x;              // 128 threads
    int v = deg_hist[127 - t];        // reversed: high degrees first
    s[t] = v;
    __syncthreads();
    for (int off = 1; off < 128; off <<= 1) {
        int x = (t >= off) ? s[t - off] : 0;
        __syncthreads();
        s[t] += x;
        __syncthreads();
    }
    deg_base[127 - t] = s[t] - v;     // exclusive prefix, descending order
}

__global__ __launch_bounds__(256) void lgcn_permplace(
    const int2* __restrict__ row_se, int* __restrict__ deg_base,
    int* __restrict__ perm) {
    __shared__ int lh[128];
    __shared__ int gb[128];
    int t = threadIdx.x;
    if (t < 128) lh[t] = 0;
    __syncthreads();
    int r = blockIdx.x * 256 + t;
    int d = 0, lp = 0;
    if (r < N_NODES) {
        int2 se = row_se[r];
        d = se.y - se.x;
        if (d > 127) d = 127;
        lp = atomicAdd(&lh[d], 1);
    }
    __syncthreads();
    if (t < 128 && lh[t]) gb[t] = atomicAdd(&deg_base[t], lh[t]);
    __syncthreads();
    if (r < N_NODES) perm[gb[d] + lp] = r;
}

// ---------------------------------------------------------------------------
// SpMM v3: 8 rows per wave, 8 lanes per row (lane owns 8 dims of one row and
// walks the row's WHOLE edge list 4-deep). No cross-lane reduction, no
// divergent tail blocks (one clamped 3-slot iteration), 64/64-active
// epilogue. Gather pattern identical to v2 (8 random 128B lines / instr).
// ---------------------------------------------------------------------------
#define FMA8(vv, uu) do {                                          \
    a[0] += (vv) * bflo((uu).x); a[1] += (vv) * bfhi((uu).x);      \
    a[2] += (vv) * bflo((uu).y); a[3] += (vv) * bfhi((uu).y);      \
    a[4] += (vv) * bflo((uu).z); a[5] += (vv) * bfhi((uu).z);      \
    a[6] += (vv) * bflo((uu).w); a[7] += (vv) * bfhi((uu).w);      \
} while (0)

#define SPMM3_BODY                                                 \
    int gid = blockIdx.x * blockDim.x + threadIdx.x;               \
    int rs = gid >> 3;                                             \
    if (rs >= N_NODES) return;                                     \
    int c = threadIdx.x & 7;                                       \
    int row = perm[rs];                                            \
    int2 se = row_se[row];                                         \
    int e = se.x;                                                  \
    int end = se.y;                                                \
    float a[8] = {0.f, 0.f, 0.f, 0.f, 0.f, 0.f, 0.f, 0.f};         \
    for (; e + 3 < end; e += 4) {                                  \
        int2 cv0 = csr_cv[e];                                      \
        int2 cv1 = csr_cv[e + 1];                                  \
        int2 cv2 = csr_cv[e + 2];                                  \
        int2 cv3 = csr_cv[e + 3];                                  \
        uint4 u0 = xb[cv0.x * 8 + c];                              \
        uint4 u1 = xb[cv1.x * 8 + c];                              \
        uint4 u2 = xb[cv2.x * 8 + c];                              \
        uint4 u3 = xb[cv3.x * 8 + c];                              \
        float v0 = __int_as_float(cv0.y);                          \
        float v1 = __int_as_float(cv1.y);                          \
        float v2 = __int_as_float(cv2.y);                          \
        float v3 = __int_as_float(cv3.y);                          \
        FMA8(v0, u0);                                              \
        FMA8(v1, u1);                                              \
        FMA8(v2, u2);                                              \
        FMA8(v3, u3);                                              \
    }                                                              \
    if (e < end) {   /* 1-3 edges left; clamp addrs, zero vals */  \
        int last = end - 1;                                        \
        int e1 = (e + 1 < end) ? e + 1 : last;                     \
        int e2 = (e + 2 < end) ? e + 2 : last;                     \
        int2 cv0 = csr_cv[e];                                      \
        int2 cv1 = csr_cv[e1];                                     \
        int2 cv2 = csr_cv[e2];                                     \
        uint4 u0 = xb[cv0.x * 8 + c];                              \
        uint4 u1 = xb[cv1.x * 8 + c];                              \
        uint4 u2 = xb[cv2.x * 8 + c];                              \
        float v0 = __int_as_float(cv0.y);                          \
        float v1 = (e + 1 < end) ? __int_as_float(cv1.y) : 0.f;    \
        float v2 = (e + 2 < end) ? __int_as_float(cv2.y) : 0.f;    \
        FMA8(v0, u0);                                              \
        FMA8(v1, u1);                                              \
        FMA8(v2, u2);                                              \
    }

__global__ __launch_bounds__(256, 8) void lgcn_spmm_bf16(
    const int* __restrict__ perm,
    const int2* __restrict__ row_se,
    const int2* __restrict__ csr_cv,
    const uint4* __restrict__ xb,
    uint4* __restrict__ yb) {
    SPMM3_BODY
    uint4 p;
    p.x = f2bf(a[0]) | (f2bf(a[1]) << 16);
    p.y = f2bf(a[2]) | (f2bf(a[3]) << 16);
    p.z = f2bf(a[4]) | (f2bf(a[5]) << 16);
    p.w = f2bf(a[6]) | (f2bf(a[7]) << 16);
    yb[row * 8 + c] = p;
}

// layer-3 variant: epilogue forms out = (x0 + y1 + y2 + y3)/4 directly.
// x0 read as bf16 from xb_a (saves 19.2MB vs fp32 inputs; error ~2^-9*|x0|).
__global__ __launch_bounds__(256, 8) void lgcn_spmm_final(
    const int* __restrict__ perm,
    const int2* __restrict__ row_se,
    const int2* __restrict__ csr_cv,
    const uint4* __restrict__ xb,     // y2 bf16 (gather input)
    const uint4* __restrict__ x0b,
    const uint4* __restrict__ y1b,
    float4* __restrict__ out) {
    SPMM3_BODY
    uint4 q0 = x0b[row * 8 + c];
    uint4 q1 = y1b[row * 8 + c];
    uint4 q2 = xb[row * 8 + c];       // y2 row (own row, one line)
    float4 o0, o1;
    o0.x = (bflo(q0.x) + bflo(q1.x) + bflo(q2.x) + a[0]) * 0.25f;
    o0.y = (bfhi(q0.x) + bfhi(q1.x) + bfhi(q2.x) + a[1]) * 0.25f;
    o0.z = (bflo(q0.y) + bflo(q1.y) + bflo(q2.y) + a[2]) * 0.25f;
    o0.w = (bfhi(q0.y) + bfhi(q1.y) + bfhi(q2.y) + a[3]) * 0.25f;
    o1.x = (bflo(q0.z) + bflo(q1.z) + bflo(q2.z) + a[4]) * 0.25f;
    o1.y = (bfhi(q0.z) + bfhi(q1.z) + bfhi(q2.z) + a[5]) * 0.25f;
    o1.z = (bflo(q0.w) + bflo(q1.w) + bflo(q2.w) + a[6]) * 0.25f;
    o1.w = (bfhi(q0.w) + bfhi(q1.w) + bfhi(q2.w) + a[7]) * 0.25f;
    int idx = row * 16 + c * 2;
    out[idx] = o0;
    out[idx + 1] = o1;
}

extern "C" void kernel_launch(void* const* d_in, const int* in_sizes, int n_in,
                              void* d_out, int out_size, void* d_ws, size_t ws_size,
                              hipStream_t stream) {
    const float* user_emb = (const float*)d_in[0];
    const float* item_emb = (const float*)d_in[1];
    const int*   adj_row  = (const int*)d_in[2];
    const int*   adj_col  = (const int*)d_in[3];
    const float* adj_vals = (const float*)d_in[4];
    float* out = (float*)d_out;

    // workspace layout (~98.8 MB, same footprint):
    //   xb_a (19.2MB) | csr_cv (38.4MB) | S (union): t_cv staging (40MB)
    //   during build; y1b+y2b (38.4MB) + perm (0.6MB) during layers | tail
    char* base = (char*)d_ws;
    uint4* xb_a   = (uint4*)base;                               // 19.2 MB
    int2*  csr_cv = (int2*)(base + 19200000);                   // 38.4 MB
    char*  S      = base + 57600000;
    const size_t T_ENTRIES = (size_t)NCB * CB_CAP;              // 4,998,000
    int2*  t_cv   = (int2*)S;                                   // 39.98 MB
    uint4* y1b    = (uint4*)S;                                  // aliases t_cv
    uint4* y2b    = (uint4*)(S + 19200000);                     // aliases t_cv
    int*   perm   = (int*)(S + 38400000);                       // 600 KB, in slack
    char*  tail   = S + T_ENTRIES * 8;
    int2*  row_se = (int2*)tail;                                // 1.2 MB
    int*   bucket_cursor = (int*)(tail + (size_t)N_NODES * 8);  // 147 ints
    int*   deg_hist = bucket_cursor + 256;                      // 128 ints
    int*   deg_base = deg_hist + 128;                           // 128 ints

    // init: xb_a = bf16(concat(user,item))
    {
        int threads = 256;
        int blocks = (N_NODES * 8 + threads - 1) / threads;
        lgcn_init<<<blocks, threads, 0, stream>>>(
            (const float4*)user_emb, (const float4*)item_emb, xb_a);
    }

    // ---- CSR build ----
    lgcn_setup<<<1, 256, 0, stream>>>(bucket_cursor, deg_hist);
    lgcn_partition<<<NTILES, 256, 0, stream>>>(
        adj_row, adj_col, adj_vals, bucket_cursor, t_cv);
    lgcn_finalize<<<NCB, 1024, 0, stream>>>(
        bucket_cursor, t_cv, csr_cv, row_se);

    // ---- degree sort (perm lives past t_cv's end-of-life) ----
    const int pblocks = (N_NODES + 255) / 256;                  // 586
    lgcn_deghist<<<pblocks, 256, 0, stream>>>(row_se, deg_hist);
    lgcn_degscan<<<1, 128, 0, stream>>>(deg_hist, deg_base);
    lgcn_permplace<<<pblocks, 256, 0, stream>>>(row_se, deg_base, perm);

    // ---- 3 propagation layers (8 rows/wave, degree-ordered) ----
    const int spmm_block = 256;
    const int spmm_grid = (N_NODES * 8 + spmm_block - 1) / spmm_block;  // 4688
    lgcn_spmm_bf16<<<spmm_grid, spmm_block, 0, stream>>>(
        perm, row_se, csr_cv, xb_a, y1b);
    lgcn_spmm_bf16<<<spmm_grid, spmm_block, 0, stream>>>(
        perm, row_se, csr_cv, y1b, y2b);
    lgcn_spmm_final<<<spmm_grid, spmm_block, 0, stream>>>(
        perm, row_se, csr_cv, y2b, xb_a, y1b, (float4*)out);
}

// Round 4
// 505.753 us; speedup vs baseline: 1.1002x; 1.1002x over previous
//
#include <hip/hip_runtime.h>

#define USER_NUM 100000
#define ITEM_NUM 50000
#define N_NODES  150000   // USER_NUM + ITEM_NUM
#define EMB_DIM  64
#define NNZ      4800000

#define CB_SHIFT 10
#define ROWS_PER_CB 1024
#define NCB ((N_NODES + ROWS_PER_CB - 1) / ROWS_PER_CB)   // 147
#define CB_CAP 34000            // expected 32.7k edges/bucket, ~7 sigma slack
#define TILE 4096
#define NTILES ((NNZ + TILE - 1) / TILE)  // 1172
#define EPT 16                  // edges per thread in partition (TILE/256)

// bf16 helpers: unpack a uint32 holding two bf16 (low ushort = even elem)
__device__ __forceinline__ float bflo(unsigned u) {
    return __uint_as_float(u << 16);
}
__device__ __forceinline__ float bfhi(unsigned u) {
    return __uint_as_float(u & 0xFFFF0000u);
}
// fp32 -> bf16 (RNE), returned in low 16 bits
__device__ __forceinline__ unsigned f2bf(float f) {
    unsigned u = __float_as_uint(f);
    return (u + 0x7FFFu + ((u >> 16) & 1u)) >> 16;
}

// ---------------------------------------------------------------------------
// init: xb = bf16(concat(user_emb, item_emb)), packed 8 elems = uint4/thread.
// ---------------------------------------------------------------------------
__global__ void lgcn_init(const float4* __restrict__ user,
                          const float4* __restrict__ item,
                          uint4* __restrict__ xb) {
    int i = blockIdx.x * blockDim.x + threadIdx.x;   // chunk of 8 floats
    if (i >= N_NODES * 8) return;
    const int user_chunks = USER_NUM * 8;
    float4 f0, f1;
    if (i < user_chunks) {
        f0 = user[i * 2];
        f1 = user[i * 2 + 1];
    } else {
        f0 = item[(i - user_chunks) * 2];
        f1 = item[(i - user_chunks) * 2 + 1];
    }
    uint4 p;
    p.x = f2bf(f0.x) | (f2bf(f0.y) << 16);
    p.y = f2bf(f0.z) | (f2bf(f0.w) << 16);
    p.z = f2bf(f1.x) | (f2bf(f1.y) << 16);
    p.w = f2bf(f1.z) | (f2bf(f1.w) << 16);
    xb[i] = p;
}

// ---------------------------------------------------------------------------
// bucket cursor init: bucket b's staging region starts at b*CB_CAP
// ---------------------------------------------------------------------------
__global__ void lgcn_bcur_init(int* __restrict__ bucket_cursor) {
    int b = blockIdx.x * blockDim.x + threadIdx.x;
    if (b < NCB) bucket_cursor[b] = b * CB_CAP;
}

// ---------------------------------------------------------------------------
// partition v2: per 4096-edge tile, in-LDS counting sort by coarse bucket.
// KEY CHANGE vs prior: col/vals are loaded COALESCED in phase C (le = tid +
// k*256 is contiguous) and scattered into LDS slot arrays; phase D reads
// only sequential LDS and issues the single coalesced t_cv write. This
// removes phase D's random 4B col[e]/vals[e] gathers (L1-miss latency storm
// that made partition cost ~a full SpMM layer).
// LDS: meta 16K + cols 16K + vls 16K + ~3K small = ~51KB -> 3 blocks/CU.
// ---------------------------------------------------------------------------
__global__ __launch_bounds__(256) void lgcn_partition(
    const int* __restrict__ row,
    const int* __restrict__ col,
    const float* __restrict__ vals,
    int* __restrict__ bucket_cursor,  // pre-init to b*CB_CAP
    int2* __restrict__ t_cv) {
    __shared__ int hist[NCB];
    __shared__ int excl[NCB];        // exclusive start, then running cursor
    __shared__ int delta[NCB];       // global pos = delta[b] + slot
    __shared__ unsigned meta[TILE];  // (b<<10) | rlo
    __shared__ int cols[TILE];
    __shared__ float vls[TILE];
    __shared__ int sscan[256];

    int tid = threadIdx.x;
    int tileStart = blockIdx.x * TILE;
    int tileCount = NNZ - tileStart;
    if (tileCount > TILE) tileCount = TILE;

    for (int b = tid; b < NCB; b += 256) hist[b] = 0;
    __syncthreads();

    // phase A: LDS bucket histogram; cache rows in regs
    int rws[EPT];
#pragma unroll
    for (int k = 0; k < EPT; ++k) {
        int le = tid + k * 256;
        int r = -1;
        if (le < tileCount) {
            r = row[tileStart + le];
            atomicAdd(&hist[r >> CB_SHIFT], 1);
        }
        rws[k] = r;
    }
    __syncthreads();

    // phase B: exclusive scan of hist (NCB=147 <= 256: one bucket per thread),
    // then reserve the global run and compute delta in the same thread.
    int h = (tid < NCB) ? hist[tid] : 0;
    sscan[tid] = h;
    __syncthreads();
    for (int off = 1; off < 256; off <<= 1) {
        int x = (tid >= off) ? sscan[tid - off] : 0;
        __syncthreads();
        sscan[tid] += x;
        __syncthreads();
    }
    if (tid < NCB) {
        int ex = sscan[tid] - h;
        excl[tid] = ex;
        int rb = h ? atomicAdd(&bucket_cursor[tid], h) : 0;
        delta[tid] = rb - ex;
    }
    __syncthreads();

    // phase C: coalesced col/val loads + LDS scatter into sorted slots
#pragma unroll
    for (int k = 0; k < EPT; ++k) {
        int le = tid + k * 256;
        if (le < tileCount) {
            int e = tileStart + le;
            int cc = col[e];          // coalesced
            float vv = vals[e];       // coalesced
            int r = rws[k];
            int b = r >> CB_SHIFT;
            int lp = atomicAdd(&excl[b], 1);
            meta[lp] = ((unsigned)b << 10) | (unsigned)(r & (ROWS_PER_CB - 1));
            cols[lp] = cc;
            vls[lp] = vv;
        }
    }
    __syncthreads();

    // phase D: sequential LDS reads, coalesced per-run global writes
    for (int i = tid; i < tileCount; i += 256) {
        unsigned m = meta[i];
        int b = m >> 10;
        int rlo = m & (ROWS_PER_CB - 1);
        int gpos = delta[b] + i;
        if (gpos < (b + 1) * CB_CAP) {   // overflow guard, statistically never
            t_cv[gpos] = make_int2((rlo << 18) | cols[i],
                                   __float_as_int(vls[i]));
        }
    }
}

// ---------------------------------------------------------------------------
// finalize: one 1024-thread block per coarse bucket. 16 waves + 4-deep load
// batching; histogram -> in-LDS scan -> row_se{start,end} -> scatter.
// (unchanged from R2, which measured ~31us)
// ---------------------------------------------------------------------------
__global__ __launch_bounds__(1024) void lgcn_finalize(
    const int* __restrict__ bucket_cursor,
    const int2* __restrict__ t_cv,
    int2* __restrict__ csr_cv,
    int2* __restrict__ row_se) {
    __shared__ int hist[ROWS_PER_CB];
    __shared__ int cur[ROWS_PER_CB];
    __shared__ int sscan[1024];
    int t = threadIdx.x;
    int b = blockIdx.x;

    // scan clamped per-bucket counts -> dense csr base + own count
    int v = 0;
    if (t < NCB) {
        int cb = bucket_cursor[t] - t * CB_CAP;
        v = (cb > CB_CAP) ? CB_CAP : cb;
    }
    if (t < 256) sscan[t] = v;
    __syncthreads();
    for (int off = 1; off < 256; off <<= 1) {
        int x = 0;
        if (t < 256 && t >= off) x = sscan[t - off];
        __syncthreads();
        if (t < 256) sscan[t] += x;
        __syncthreads();
    }
    int prev = (b == 0) ? 0 : sscan[b - 1];
    int bbase = prev;                 // dense CSR base of this bucket
    int count = sscan[b] - prev;      // clamped edge count of this bucket
    __syncthreads();

    int lo = b * ROWS_PER_CB;
    int nrows = N_NODES - lo;
    if (nrows > ROWS_PER_CB) nrows = ROWS_PER_CB;

    hist[t] = 0;
    __syncthreads();

    // pass 1: per-row histogram, 4 loads in flight per thread
    int base = b * CB_CAP;
    int eEnd = base + count;
    int e = base + t;
    for (; e + 3 * 1024 < eEnd; e += 4 * 1024) {
        int2 c0 = t_cv[e];
        int2 c1 = t_cv[e + 1024];
        int2 c2 = t_cv[e + 2048];
        int2 c3 = t_cv[e + 3072];
        atomicAdd(&hist[(unsigned)c0.x >> 18], 1);
        atomicAdd(&hist[(unsigned)c1.x >> 18], 1);
        atomicAdd(&hist[(unsigned)c2.x >> 18], 1);
        atomicAdd(&hist[(unsigned)c3.x >> 18], 1);
    }
    for (; e < eEnd; e += 1024)
        atomicAdd(&hist[(unsigned)t_cv[e].x >> 18], 1);
    __syncthreads();

    // scan hist[1024], one element per thread
    int h = hist[t];
    sscan[t] = h;
    __syncthreads();
    for (int off = 1; off < 1024; off <<= 1) {
        int x = (t >= off) ? sscan[t - off] : 0;
        __syncthreads();
        sscan[t] += x;
        __syncthreads();
    }
    int p = bbase + sscan[t] - h;     // exclusive prefix within bucket
    if (t < nrows) {
        row_se[lo + t] = make_int2(p, p + h);
        cur[t] = p;
    }
    __syncthreads();

    // pass 2: scatter into dense CSR (segment re-read hits L2)
    e = base + t;
    for (; e + 3 * 1024 < eEnd; e += 4 * 1024) {
        int2 c0 = t_cv[e];
        int2 c1 = t_cv[e + 1024];
        int2 c2 = t_cv[e + 2048];
        int2 c3 = t_cv[e + 3072];
        int p0 = atomicAdd(&cur[(unsigned)c0.x >> 18], 1);
        int p1 = atomicAdd(&cur[(unsigned)c1.x >> 18], 1);
        int p2 = atomicAdd(&cur[(unsigned)c2.x >> 18], 1);
        int p3 = atomicAdd(&cur[(unsigned)c3.x >> 18], 1);
        csr_cv[p0] = make_int2(c0.x & 0x3FFFF, c0.y);
        csr_cv[p1] = make_int2(c1.x & 0x3FFFF, c1.y);
        csr_cv[p2] = make_int2(c2.x & 0x3FFFF, c2.y);
        csr_cv[p3] = make_int2(c3.x & 0x3FFFF, c3.y);
    }
    for (; e < eEnd; e += 1024) {
        int2 cv = t_cv[e];
        int pos = atomicAdd(&cur[(unsigned)cv.x >> 18], 1);
        csr_cv[pos] = make_int2(cv.x & 0x3FFFF, cv.y);
    }
}

// ---------------------------------------------------------------------------
// SpMM v2 (best measured): one wave per row. Lanes = 8 edge-subgroups x 8
// dim-chunks; each lane loads 16B = 8 bf16 of x[col]; a row is ONE 128B line.
// ---------------------------------------------------------------------------
#define FMA8(vv, uu) do {                                          \
    a[0] += (vv) * bflo((uu).x); a[1] += (vv) * bfhi((uu).x);      \
    a[2] += (vv) * bflo((uu).y); a[3] += (vv) * bfhi((uu).y);      \
    a[4] += (vv) * bflo((uu).z); a[5] += (vv) * bfhi((uu).z);      \
    a[6] += (vv) * bflo((uu).w); a[7] += (vv) * bfhi((uu).w);      \
} while (0)

#define SPMM_BODY                                                  \
    int gid = blockIdx.x * blockDim.x + threadIdx.x;               \
    int r = gid >> 6;                                              \
    if (r >= N_NODES) return;                                      \
    int lane = threadIdx.x & 63;                                   \
    int c = lane & 7;                                              \
    int sub = lane >> 3;                                           \
    int2 se = row_se[r];                                           \
    int start = se.x;                                              \
    int end = se.y;                                                \
    float a[8] = {0.f, 0.f, 0.f, 0.f, 0.f, 0.f, 0.f, 0.f};         \
    int e = start + sub;                                           \
    for (; e + 24 < end; e += 32) {                                \
        int2 cv0 = csr_cv[e];                                      \
        int2 cv1 = csr_cv[e + 8];                                  \
        int2 cv2 = csr_cv[e + 16];                                 \
        int2 cv3 = csr_cv[e + 24];                                 \
        uint4 u0 = xb[cv0.x * 8 + c];                              \
        uint4 u1 = xb[cv1.x * 8 + c];                              \
        uint4 u2 = xb[cv2.x * 8 + c];                              \
        uint4 u3 = xb[cv3.x * 8 + c];                              \
        float v0 = __int_as_float(cv0.y);                          \
        float v1 = __int_as_float(cv1.y);                          \
        float v2 = __int_as_float(cv2.y);                          \
        float v3 = __int_as_float(cv3.y);                          \
        FMA8(v0, u0);                                              \
        FMA8(v1, u1);                                              \
        FMA8(v2, u2);                                              \
        FMA8(v3, u3);                                              \
    }                                                              \
    if (e + 8 < end) {                                             \
        int2 cv0 = csr_cv[e];                                      \
        int2 cv1 = csr_cv[e + 8];                                  \
        uint4 u0 = xb[cv0.x * 8 + c];                              \
        uint4 u1 = xb[cv1.x * 8 + c];                              \
        float v0 = __int_as_float(cv0.y);                          \
        float v1 = __int_as_float(cv1.y);                          \
        FMA8(v0, u0);                                              \
        FMA8(v1, u1);                                              \
        e += 16;                                                   \
    }                                                              \
    if (e < end) {                                                 \
        int2 cv = csr_cv[e];                                       \
        uint4 u = xb[cv.x * 8 + c];                                \
        float v = __int_as_float(cv.y);                            \
        FMA8(v, u);                                                \
    }                                                              \
    _Pragma("unroll")                                              \
    for (int k = 0; k < 8; ++k) {                                  \
        a[k] += __shfl_xor(a[k], 8);                               \
        a[k] += __shfl_xor(a[k], 16);                              \
        a[k] += __shfl_xor(a[k], 32);                              \
    }

__global__ __launch_bounds__(256, 8) void lgcn_spmm_bf16(
    const int2* __restrict__ row_se,
    const int2* __restrict__ csr_cv,
    const uint4* __restrict__ xb,
    uint4* __restrict__ yb) {
    SPMM_BODY
    if (sub == 0) {
        uint4 p;
        p.x = f2bf(a[0]) | (f2bf(a[1]) << 16);
        p.y = f2bf(a[2]) | (f2bf(a[3]) << 16);
        p.z = f2bf(a[4]) | (f2bf(a[5]) << 16);
        p.w = f2bf(a[6]) | (f2bf(a[7]) << 16);
        yb[r * 8 + c] = p;
    }
}

// layer-3 variant: epilogue forms out = (x0 + y1 + y2 + y3)/4 directly.
// x0 read as bf16 from xb_a (-19.2MB vs fp32 inputs; absmax verified same).
__global__ __launch_bounds__(256, 8) void lgcn_spmm_final(
    const int2* __restrict__ row_se,
    const int2* __restrict__ csr_cv,
    const uint4* __restrict__ xb,     // y2 bf16 (gather input)
    const uint4* __restrict__ x0b,
    const uint4* __restrict__ y1b,
    float4* __restrict__ out) {
    SPMM_BODY
    if (sub == 0) {
        uint4 q0 = x0b[r * 8 + c];
        uint4 q1 = y1b[r * 8 + c];
        uint4 q2 = xb[r * 8 + c];     // y2 row (own row, one line)
        float4 o0, o1;
        o0.x = (bflo(q0.x) + bflo(q1.x) + bflo(q2.x) + a[0]) * 0.25f;
        o0.y = (bfhi(q0.x) + bfhi(q1.x) + bfhi(q2.x) + a[1]) * 0.25f;
        o0.z = (bflo(q0.y) + bflo(q1.y) + bflo(q2.y) + a[2]) * 0.25f;
        o0.w = (bfhi(q0.y) + bfhi(q1.y) + bfhi(q2.y) + a[3]) * 0.25f;
        o1.x = (bflo(q0.z) + bflo(q1.z) + bflo(q2.z) + a[4]) * 0.25f;
        o1.y = (bfhi(q0.z) + bfhi(q1.z) + bfhi(q2.z) + a[5]) * 0.25f;
        o1.z = (bflo(q0.w) + bflo(q1.w) + bflo(q2.w) + a[6]) * 0.25f;
        o1.w = (bfhi(q0.w) + bfhi(q1.w) + bfhi(q2.w) + a[7]) * 0.25f;
        int idx = r * 16 + c * 2;
        out[idx] = o0;
        out[idx + 1] = o1;
    }
}

extern "C" void kernel_launch(void* const* d_in, const int* in_sizes, int n_in,
                              void* d_out, int out_size, void* d_ws, size_t ws_size,
                              hipStream_t stream) {
    const float* user_emb = (const float*)d_in[0];
    const float* item_emb = (const float*)d_in[1];
    const int*   adj_row  = (const int*)d_in[2];
    const int*   adj_col  = (const int*)d_in[3];
    const float* adj_vals = (const float*)d_in[4];
    float* out = (float*)d_out;

    // workspace layout (~98.8 MB, unchanged footprint):
    //   xb_a (19.2MB) | csr_cv (38.4MB) | S (union): t_cv staging (40MB)
    //   during build; y1b (19.2MB) + y2b (19.2MB) during layers | row_se
    char* base = (char*)d_ws;
    uint4* xb_a   = (uint4*)base;                               // 19.2 MB
    int2*  csr_cv = (int2*)(base + 19200000);                   // 38.4 MB
    char*  S      = base + 57600000;
    const size_t T_ENTRIES = (size_t)NCB * CB_CAP;              // 4,998,000
    int2*  t_cv   = (int2*)S;                                   // 40.0 MB
    uint4* y1b    = (uint4*)S;                                  // aliases t_cv
    uint4* y2b    = (uint4*)(S + 19200000);                     // aliases t_cv
    char*  tail   = S + T_ENTRIES * 8;
    int2*  row_se = (int2*)tail;                                // 1.2 MB
    int*   bucket_cursor = (int*)(tail + (size_t)N_NODES * 8);  // 147 ints

    // init: xb_a = bf16(concat(user,item))
    {
        int threads = 256;
        int blocks = (N_NODES * 8 + threads - 1) / threads;
        lgcn_init<<<blocks, threads, 0, stream>>>(
            (const float4*)user_emb, (const float4*)item_emb, xb_a);
    }

    // ---- CSR build: partition (LDS-staged col/vals) -> fused finalize ----
    lgcn_bcur_init<<<1, 256, 0, stream>>>(bucket_cursor);
    lgcn_partition<<<NTILES, 256, 0, stream>>>(
        adj_row, adj_col, adj_vals, bucket_cursor, t_cv);
    lgcn_finalize<<<NCB, 1024, 0, stream>>>(
        bucket_cursor, t_cv, csr_cv, row_se);

    // ---- 3 propagation layers (v2 SpMM, one wave per row) ----
    const int spmm_block = 256;                       // 4 waves = 4 rows / block
    const int spmm_grid = (N_NODES * 64 + spmm_block - 1) / spmm_block;
    lgcn_spmm_bf16<<<spmm_grid, spmm_block, 0, stream>>>(
        row_se, csr_cv, xb_a, y1b);
    lgcn_spmm_bf16<<<spmm_grid, spmm_block, 0, stream>>>(
        row_se, csr_cv, y1b, y2b);
    lgcn_spmm_final<<<spmm_grid, spmm_block, 0, stream>>>(
        row_se, csr_cv, y2b, xb_a, y1b, (float4*)out);
}